// Round 10
// baseline (127.576 us; speedup 1.0000x reference)
//
#include <hip/hip_runtime.h>

// Problem constants
#define BB 256
#define PP 128
#define KK 16
#define HH 128
#define OO 256
#define EE 18      // 2*(C+F)
#define XCH 10     // C + F + 1 (coords, feats, mask)
#define BIGD 1000000000.0f
#define GPT 8      // points per WG (4 waves x 2 points/wave)
#define NBLK ((BB * PP) / GPT)  // 4096

typedef __bf16 bf16x8 __attribute__((ext_vector_type(8)));
typedef __bf16 bf16x4 __attribute__((ext_vector_type(4)));
typedef float  f32x4  __attribute__((ext_vector_type(4)));
typedef unsigned long long ull;

// ---------------------------------------------------------------------------
// Kernel 1: pack W2 and W1 into bf16 MFMA fragment order.
// W2p (B-frag, 16x16x32): [ct 16][ks 4][lane 64][j 8], elem = W2[ks*32+(l>>4)*8+j][ct*16+(l&15)]
// W1p (A-frag for h1^T = W1^T @ edge^T): [nt 8][lane 64][j 8],
//   elem = W1[k][nt*16+(l&15)] for k=(l>>4)*8+j < 18, else 0 (K padded to 32).
// ---------------------------------------------------------------------------
__global__ __launch_bounds__(256) void pack_w_kernel(const float* __restrict__ W1,
                                                     const float* __restrict__ W2,
                                                     __bf16* __restrict__ W2p,
                                                     __bf16* __restrict__ W1p) {
    const int t = blockIdx.x * 256 + threadIdx.x;  // 0 .. 36863
    if (t < 32768) {
        const int j  = t & 7;
        const int l  = (t >> 3) & 63;
        const int ks = (t >> 9) & 3;
        const int ct = t >> 11;
        const int row = ks * 32 + ((l >> 4) * 8) + j;
        const int col = ct * 16 + (l & 15);
        W2p[t] = (__bf16)W2[row * OO + col];
    } else {
        const int t2 = t - 32768;  // 0 .. 4095
        const int j  = t2 & 7;
        const int l  = (t2 >> 3) & 63;
        const int nt = t2 >> 9;
        const int k  = ((l >> 4) * 8) + j;
        const int n  = nt * 16 + (l & 15);
        W1p[t2] = (k < EE) ? (__bf16)W1[k * HH + n] : (__bf16)0.0f;
    }
}

// ---------------------------------------------------------------------------
// Kernel 2: fully-fused EdgeConv: per-block KNN + edge-MLP (all-MFMA).
//
// DE-SCRATCH revision of r9. Evidence (r0-r9): residency is pinned at ~2
// WG/CU in EVERY configuration (even r2's persistent 8-WG/CU grid), while
// declared VGPR/LDS permit 4+. The one invisible resource with exactly that
// signature is SCRATCH (private segment): if allocated, concurrent waves are
// clamped by scratch-ring sizing regardless of VGPR/LDS. A known compiler
// trap present in all 10 prior variants: KNN select state held in ARRAYS
// (A0[2], need[2], ...) mutated through a [&]-capturing LAMBDA inside a
// '#pragma unroll 1' runtime loop -- if SROA fails, these silently land in
// scratch (guide rule #20). This revision mechanically de-arrays and
// de-lambdas the whole select path: named scalars per point (suffix A/B),
// macro round bodies, duplicated blocks. NO algorithmic change; numerics
// and winner sets bit-identical to r9.
// ---------------------------------------------------------------------------

// one radix-4 round for one point's state (references loop var `t`)
#define RROUND(vA0, vA1, vW0, vW1, vneed, vasz, vdb0, vdb1)                    \
    if (vneed) {                                                               \
        const unsigned dg0 = ((vdb0) >> (2 * t + 1)) & 3u;                     \
        const unsigned dg1 = ((vdb1) >> (2 * t + 1)) & 3u;                     \
        const ull p0_0  = __ballot(dg0 == 0u);                                 \
        const ull p1_0  = __ballot(dg1 == 0u);                                 \
        const ull p0_01 = __ballot(dg0 <= 1u);                                 \
        const ull p1_01 = __ballot(dg1 <= 1u);                                 \
        const ull p0_02 = __ballot(dg0 <= 2u);                                 \
        const ull p1_02 = __ballot(dg1 <= 2u);                                 \
        const ull z0_0  = (vA0) & p0_0,  z1_0  = (vA1) & p1_0;                 \
        const ull z0_01 = (vA0) & p0_01, z1_01 = (vA1) & p1_01;                \
        const ull z0_02 = (vA0) & p0_02, z1_02 = (vA1) & p1_02;                \
        const int c0c = __popcll(z0_0)  + __popcll(z1_0);                      \
        const int c01 = __popcll(z0_01) + __popcll(z1_01);                     \
        const int c02 = __popcll(z0_02) + __popcll(z1_02);                     \
        if (c0c >= (vneed)) {                                                  \
            vA0 = z0_0; vA1 = z1_0; vasz = c0c;                                \
        } else if (c01 >= (vneed)) {                                           \
            vW0 |= z0_0; vW1 |= z1_0; vneed -= c0c;                            \
            vA0 = z0_01 & ~p0_0; vA1 = z1_01 & ~p1_0; vasz = c01 - c0c;        \
        } else if (c02 >= (vneed)) {                                           \
            vW0 |= z0_01; vW1 |= z1_01; vneed -= c01;                          \
            vA0 = z0_02 & ~p0_01; vA1 = z1_02 & ~p1_01; vasz = c02 - c01;      \
        } else {                                                               \
            vW0 |= z0_02; vW1 |= z1_02; vneed -= c02;                          \
            vA0 &= ~p0_02; vA1 &= ~p1_02; vasz -= c02;                         \
        }                                                                      \
        if (vasz == (vneed)) {                                                 \
            vW0 |= vA0; vW1 |= vA1; vA0 = 0ull; vA1 = 0ull; vneed = 0;         \
        }                                                                      \
    }

// one refinement step (phases A'/B) for one point's state
#define SSTEP(vA0, vA1, vW0, vW1, vneed, vasz, q0, q1)                         \
    {                                                                          \
        const ull z0 = (vA0) & (q0);                                           \
        const ull z1 = (vA1) & (q1);                                           \
        const int c = __popcll(z0) + __popcll(z1);                             \
        if (c == (vneed)) { vW0 |= z0; vW1 |= z1; vA0 = 0ull; vA1 = 0ull; vneed = 0; } \
        else if (c > (vneed)) { vA0 = z0; vA1 = z1; vasz = c; }                \
        else { vW0 |= z0; vW1 |= z1; vneed -= c; vA0 &= ~z0; vA1 &= ~z1; vasz -= c; } \
    }

__global__ __launch_bounds__(256, 4) void mlp_kernel(const float* __restrict__ x,
                                                     const __bf16* __restrict__ W1p,
                                                     const float* __restrict__ b1,
                                                     const __bf16* __restrict__ W2p,
                                                     const float* __restrict__ b2,
                                                     float* __restrict__ out) {
    __shared__ __bf16 sh1A[4 * GPT * 64 * 8];  // [ks4][g8][lane][j], 32 KB
    __shared__ int    sknn[GPT][KK];           // per-point winner slots

    const int tid = threadIdx.x;
    const int lane = tid & 63;
    const int w = tid >> 6;          // 0..3
    const int quad = lane >> 4;
    const int lcol = lane & 15;

    const int pbase = blockIdx.x * GPT;
    const int bidx = pbase >> 7;
    const int i0 = pbase & (PP - 1);           // 16 WGs per batch item
    const float* xb = x + (size_t)bidx * PP * XCH;
    float* outrow = out + (size_t)pbase * (OO + 1);

    // ---- candidate rows (these loads start the wave; nothing precedes) ----
    const int j0 = lane, j1 = lane + 64;
    const float2 c0 = *(const float2*)(xb + j0 * XCH);
    const float  m0 = xb[j0 * XCH + (XCH - 1)];
    const float2 c1 = *(const float2*)(xb + j1 * XCH);
    const float  m1 = xb[j1 * XCH + (XCH - 1)];

    // ---- GEMM1 A-fragments + center rows: issued early, consumed late ----
    bf16x8 wf[8];
#pragma unroll
    for (int nt = 0; nt < 8; ++nt)
        wf[nt] = *(const bf16x8*)&W1p[(size_t)((nt * 64 + lane) * 8)];

    const int iA = i0 + w * 2, iB = iA + 1;
    const float* ciA = xb + iA * XCH;   // wave-uniform
    const float* ciB = xb + iB * XCH;
    const float2 a01A = *(const float2*)(ciA + 0);
    const float2 a23A = *(const float2*)(ciA + 2);
    const float2 a45A = *(const float2*)(ciA + 4);
    const float2 a67A = *(const float2*)(ciA + 6);
    const float  a8A  = ciA[8];
    const float2 a01B = *(const float2*)(ciB + 0);
    const float2 a23B = *(const float2*)(ciB + 2);
    const float2 a45B = *(const float2*)(ciB + 4);
    const float2 a67B = *(const float2*)(ciB + 6);
    const float  a8B  = ciB[8];

    // ---- validity bits from ballots (mask is exactly 0.0/1.0) ----
    const ull B0 = __ballot(m0 != 0.0f);   // rows 0..63
    const ull B1 = __ballot(m1 != 0.0f);   // rows 64..127
    const ull selB = (i0 & 64) ? B1 : B0;  // this WG's 8 rows are in one half
    const unsigned vbits = (unsigned)((selB >> (i0 & 63)) & 0xFFull);
    if (vbits == 0u) {
        // out is re-poisoned before every launch: must write zeros
        for (int o = tid; o < GPT * (OO + 1); o += 256) outrow[o] = 0.0f;
        return;  // wave/block-uniform: no barrier mismatch
    }

    // ---- centers via shuffle from candidate regs (bit-identical) ----
    const bool hiA = (iA & 64) != 0;       // iA,iB in the same half (i0%8==0)
    const float selx = hiA ? c1.x : c0.x;
    const float sely = hiA ? c1.y : c0.y;
    const float ccAx = __shfl(selx, iA & 63, 64);
    const float ccAy = __shfl(sely, iA & 63, 64);
    const float ccBx = __shfl(selx, iB & 63, 64);
    const float ccBy = __shfl(sely, iB & 63, 64);

    // ================= KNN: 2 radix-4 selects batched through one loop =====
    // key = (d_bits<<7)|j, ascending == jax.lax.top_k stable order; self
    // excluded via BIGD; dist2 via __fmul_rn/__fadd_rn matches numpy.
    unsigned db0A, db1A, db0B, db1B;
    {
        float dx, dy, d;
        dx = ccAx - c0.x; dy = ccAy - c0.y;
        d = __fadd_rn(__fmul_rn(dx, dx), __fmul_rn(dy, dy));
        if (m0 <= 0.0f || j0 == iA) d = BIGD;
        db0A = __float_as_uint(d);
        dx = ccAx - c1.x; dy = ccAy - c1.y;
        d = __fadd_rn(__fmul_rn(dx, dx), __fmul_rn(dy, dy));
        if (m1 <= 0.0f || j1 == iA) d = BIGD;
        db1A = __float_as_uint(d);
        dx = ccBx - c0.x; dy = ccBy - c0.y;
        d = __fadd_rn(__fmul_rn(dx, dx), __fmul_rn(dy, dy));
        if (m0 <= 0.0f || j0 == iB) d = BIGD;
        db0B = __float_as_uint(d);
        dx = ccBx - c1.x; dy = ccBy - c1.y;
        d = __fadd_rn(__fmul_rn(dx, dx), __fmul_rn(dy, dy));
        if (m1 <= 0.0f || j1 == iB) d = BIGD;
        db1B = __float_as_uint(d);
    }

    ull A0A = ~0ull, A1A = ~0ull, W0A = 0ull, W1A = 0ull;
    ull A0B = ~0ull, A1B = ~0ull, W0B = 0ull, W1B = 0ull;
    int needA = ((vbits >> (w * 2 + 0)) & 1u) ? KK : 0;
    int needB = ((vbits >> (w * 2 + 1)) & 1u) ? KK : 0;
    int aszA = 128, aszB = 128;

    // phase A: radix-4 digits over d bits (30,29),(28,27),...,(2,1)
#pragma unroll 1
    for (int t = 14; t >= 0; --t) {
        RROUND(A0A, A1A, W0A, W1A, needA, aszA, db0A, db1A)
        RROUND(A0B, A1B, W0B, W1B, needB, aszB, db0B, db1B)
        if (!(needA | needB)) break;
    }
    // phases A' (last d bit) + B (index bits 6..0), per point
    {
        const ull M5 = 0x00000000FFFFFFFFull;
        const ull M4 = 0x0000FFFF0000FFFFull;
        const ull M3 = 0x00FF00FF00FF00FFull;
        const ull M2 = 0x0F0F0F0F0F0F0F0Full;
        const ull M1 = 0x3333333333333333ull;
        const ull M0 = 0x5555555555555555ull;
        if (needA) {
            const ull q0 = __ballot((db0A & 1u) == 0u);
            const ull q1 = __ballot((db1A & 1u) == 0u);
            SSTEP(A0A, A1A, W0A, W1A, needA, aszA, q0, q1)
        }
        if (needA) SSTEP(A0A, A1A, W0A, W1A, needA, aszA, ~0ull, 0ull)
        if (needA) SSTEP(A0A, A1A, W0A, W1A, needA, aszA, M5, M5)
        if (needA) SSTEP(A0A, A1A, W0A, W1A, needA, aszA, M4, M4)
        if (needA) SSTEP(A0A, A1A, W0A, W1A, needA, aszA, M3, M3)
        if (needA) SSTEP(A0A, A1A, W0A, W1A, needA, aszA, M2, M2)
        if (needA) SSTEP(A0A, A1A, W0A, W1A, needA, aszA, M1, M1)
        if (needA) SSTEP(A0A, A1A, W0A, W1A, needA, aszA, M0, M0)
        W0A |= A0A; W1A |= A1A;   // keys unique => remaining = rest

        if (needB) {
            const ull q0 = __ballot((db0B & 1u) == 0u);
            const ull q1 = __ballot((db1B & 1u) == 0u);
            SSTEP(A0B, A1B, W0B, W1B, needB, aszB, q0, q1)
        }
        if (needB) SSTEP(A0B, A1B, W0B, W1B, needB, aszB, ~0ull, 0ull)
        if (needB) SSTEP(A0B, A1B, W0B, W1B, needB, aszB, M5, M5)
        if (needB) SSTEP(A0B, A1B, W0B, W1B, needB, aszB, M4, M4)
        if (needB) SSTEP(A0B, A1B, W0B, W1B, needB, aszB, M3, M3)
        if (needB) SSTEP(A0B, A1B, W0B, W1B, needB, aszB, M2, M2)
        if (needB) SSTEP(A0B, A1B, W0B, W1B, needB, aszB, M1, M1)
        if (needB) SSTEP(A0B, A1B, W0B, W1B, needB, aszB, M0, M0)
        W0B |= A0B; W1B |= A1B;
    }

    // ---- winner compaction into sknn (per point) ----
    if ((vbits >> (w * 2 + 0)) & 1u) {
        unsigned int mb0 = __builtin_amdgcn_mbcnt_lo((unsigned)(W0A & 0xffffffffull), 0u);
        mb0 = __builtin_amdgcn_mbcnt_hi((unsigned)(W0A >> 32), mb0);
        unsigned int mb1 = __builtin_amdgcn_mbcnt_lo((unsigned)(W1A & 0xffffffffull), 0u);
        mb1 = __builtin_amdgcn_mbcnt_hi((unsigned)(W1A >> 32), mb1);
        const int base1 = __popcll(W0A);
        if ((W0A >> lane) & 1ull) sknn[w * 2 + 0][mb0] = j0;
        if ((W1A >> lane) & 1ull) sknn[w * 2 + 0][base1 + mb1] = j1;
    } else {
        if (lane < KK) sknn[w * 2 + 0][lane] = 0;  // dummy valid indices
    }
    if ((vbits >> (w * 2 + 1)) & 1u) {
        unsigned int mb0 = __builtin_amdgcn_mbcnt_lo((unsigned)(W0B & 0xffffffffull), 0u);
        mb0 = __builtin_amdgcn_mbcnt_hi((unsigned)(W0B >> 32), mb0);
        unsigned int mb1 = __builtin_amdgcn_mbcnt_lo((unsigned)(W1B & 0xffffffffull), 0u);
        mb1 = __builtin_amdgcn_mbcnt_hi((unsigned)(W1B >> 32), mb1);
        const int base1 = __popcll(W0B);
        if ((W0B >> lane) & 1ull) sknn[w * 2 + 1][mb0] = j0;
        if ((W1B >> lane) & 1ull) sknn[w * 2 + 1][base1 + mb1] = j1;
    } else {
        if (lane < KK) sknn[w * 2 + 1][lane] = 0;
    }
    // NO barrier: wave reads only its own sknn rows (DS in-order per wave)

    // ============ gather both points' neighbor rows, then GEMM1 x2 =========
    const int jnA = sknn[w * 2 + 0][lcol];
    const int jnB = sknn[w * 2 + 1][lcol];
    const float* cjA = xb + jnA * XCH;
    const float* cjB = xb + jnB * XCH;
    const float2 n01A = *(const float2*)(cjA + 0);
    const float2 n23A = *(const float2*)(cjA + 2);
    const float2 n45A = *(const float2*)(cjA + 4);
    const float2 n67A = *(const float2*)(cjA + 6);
    const float  n8A  = cjA[8];
    const float2 n01B = *(const float2*)(cjB + 0);
    const float2 n23B = *(const float2*)(cjB + 2);
    const float2 n45B = *(const float2*)(cjB + 4);
    const float2 n67B = *(const float2*)(cjB + 6);
    const float  n8B  = cjB[8];

    const f32x4 z4 = {0.0f, 0.0f, 0.0f, 0.0f};

#define EDGE_G1(g, a01, a23, a45, a67, a8, n01, n23, n45, n67, n8)             \
    {                                                                          \
        float v0 = 0.0f, v1 = 0.0f, v2 = 0.0f, v3 = 0.0f;                      \
        float v4 = 0.0f, v5 = 0.0f, v6 = 0.0f, v7 = 0.0f;                      \
        if (quad == 0) {                                                       \
            v0 = (a01).x; v1 = (a01).y; v2 = (a23).x; v3 = (a23).y;            \
            v4 = (a45).x; v5 = (a45).y; v6 = (a67).x; v7 = (a67).y;            \
        } else if (quad == 1) {                                                \
            v0 = (a8);                                                         \
            v1 = (n01).x - (a01).x; v2 = (n01).y - (a01).y;                    \
            v3 = (n23).x - (a23).x; v4 = (n23).y - (a23).y;                    \
            v5 = (n45).x - (a45).x; v6 = (n45).y - (a45).y;                    \
            v7 = (n67).x - (a67).x;                                            \
        } else if (quad == 2) {                                                \
            v0 = (n67).y - (a67).y;                                            \
            v1 = (n8) - (a8);                                                  \
        }                                                                      \
        bf16x8 ef;                                                             \
        ef[0] = (__bf16)v0; ef[1] = (__bf16)v1; ef[2] = (__bf16)v2;            \
        ef[3] = (__bf16)v3; ef[4] = (__bf16)v4; ef[5] = (__bf16)v5;            \
        ef[6] = (__bf16)v6; ef[7] = (__bf16)v7;                                \
        f32x4 hh[8];                                                           \
        _Pragma("unroll")                                                      \
        for (int nt = 0; nt < 8; ++nt)                                         \
            hh[nt] = __builtin_amdgcn_mfma_f32_16x16x32_bf16(wf[nt], ef, z4, 0, 0, 0); \
        _Pragma("unroll")                                                      \
        for (int nt = 0; nt < 8; ++nt) {                                       \
            const int ks = nt >> 1;                                            \
            const int lp = (((nt * 2 + (quad >> 1)) & 3) << 4) | lcol;         \
            const f32x4 b1v = *(const f32x4*)&b1[nt * 16 + quad * 4];          \
            bf16x4 hv;                                                         \
            _Pragma("unroll")                                                  \
            for (int r = 0; r < 4; ++r)                                        \
                hv[r] = (__bf16)fmaxf(hh[nt][r] + b1v[r], 0.0f);               \
            *(bf16x4*)&sh1A[((ks * GPT + (g)) * 64 + lp) * 8 + (quad & 1) * 4] = hv; \
        }                                                                      \
    }

    EDGE_G1(w * 2 + 0, a01A, a23A, a45A, a67A, a8A, n01A, n23A, n45A, n67A, n8A)
    EDGE_G1(w * 2 + 1, a01B, a23B, a45B, a67B, a8B, n01B, n23B, n45B, n67B, n8B)
    __syncthreads();

    // ---- GEMM2 (MFMA): 8 points x 256 cols, wave w owns cols w*64.. -------
    // bfr hoisted across gg (W2p frag reads 16/wave); acc live-set 32 f32
    // regs per gg sub-block; B-frags WG-shared. Static-unrolled arrays only.
#pragma unroll
    for (int ch = 0; ch < 2; ++ch) {
        bf16x8 bfr[4][2];
#pragma unroll
        for (int ks = 0; ks < 4; ++ks)
#pragma unroll
            for (int c = 0; c < 2; ++c)
                bfr[ks][c] = *(const bf16x8*)&W2p[(size_t)((((w * 4 + ch * 2 + c) * 4 + ks) * 64 + lane) * 8)];

#pragma unroll
        for (int gg = 0; gg < 2; ++gg) {
            f32x4 acc[4][2];
#pragma unroll
            for (int gi = 0; gi < 4; ++gi) { acc[gi][0] = z4; acc[gi][1] = z4; }

#pragma unroll
            for (int ks = 0; ks < 4; ++ks) {
                bf16x8 af[4];
#pragma unroll
                for (int gi = 0; gi < 4; ++gi)
                    af[gi] = *(const bf16x8*)&sh1A[((ks * GPT + gg * 4 + gi) * 64 + lane) * 8];
#pragma unroll
                for (int gi = 0; gi < 4; ++gi)
#pragma unroll
                    for (int c = 0; c < 2; ++c)
                        acc[gi][c] = __builtin_amdgcn_mfma_f32_16x16x32_bf16(
                            af[gi], bfr[ks][c], acc[gi][c], 0, 0, 0);
            }

            // epilogue 2: relu(+b2), K-sum = tile column sum via shuffles
#pragma unroll
            for (int c = 0; c < 2; ++c) {
                const int col = w * 64 + (ch * 2 + c) * 16 + lcol;
                const float bc = b2[col];
                float val = 0.0f;
#pragma unroll
                for (int gi = 0; gi < 4; ++gi) {
                    float s = 0.0f;
#pragma unroll
                    for (int r = 0; r < 4; ++r) s += fmaxf(acc[gi][c][r] + bc, 0.0f);
                    s += __shfl_xor(s, 16, 64);
                    s += __shfl_xor(s, 32, 64);
                    if (quad == gi) val = s;   // lane (quad=gi,lcol) keeps
                }
                const float mscale =
                    ((vbits >> (gg * 4 + quad)) & 1u) ? (1.0f / KK) : 0.0f;
                outrow[(size_t)(gg * 4 + quad) * (OO + 1) + col] = val * mscale;
            }
        }
    }
    if (tid < GPT)
        outrow[(size_t)tid * (OO + 1) + OO] = ((vbits >> tid) & 1u) ? 1.0f : 0.0f;
}

extern "C" void kernel_launch(void* const* d_in, const int* in_sizes, int n_in,
                              void* d_out, int out_size, void* d_ws, size_t ws_size,
                              hipStream_t stream) {
    const float* x  = (const float*)d_in[0];
    const float* W1 = (const float*)d_in[1];
    const float* b1 = (const float*)d_in[2];
    const float* W2 = (const float*)d_in[3];
    const float* b2 = (const float*)d_in[4];
    float* out = (float*)d_out;

    __bf16* W2p = (__bf16*)d_ws;                    // 64 KB
    __bf16* W1p = (__bf16*)((char*)d_ws + 65536);   // 8 KB

    pack_w_kernel<<<144, 256, 0, stream>>>(W1, W2, W2p, W1p);

    mlp_kernel<<<NBLK, 256, 0, stream>>>(x, W1p, b1, W2p, b2, out);
}